// Round 6
// baseline (104.529 us; speedup 1.0000x reference)
//
#include <hip/hip_runtime.h>
#include <hip/hip_bf16.h>

#define B_DIM 16384
#define P_DIM 4096
#define D_DIM 256

typedef float f32x4 __attribute__((ext_vector_type(4)));
typedef __bf16 bf16x8 __attribute__((ext_vector_type(8)));

__device__ __forceinline__ unsigned short f2bf_rne(float f) {
  unsigned int u = __builtin_bit_cast(unsigned int, f);
  u += 0x7fffu + ((u >> 16) & 1u);
  return (unsigned short)(u >> 16);
}

// Prep: one 256-thread block per 16-row group. Emits bf16 in fragment-
// interleaved layout A'[rg][kc][r16][8] (kc = k/8) so GEMM fragment loads
// are fully coalesced 1KB reads. Also computes fp32 row sum-of-squares.
// Thread t: row = t>>4 (0..15), kq = t&15 (k-quad); 4 passes over k.
__global__ __launch_bounds__(256) void prep_kernel(
    const float* __restrict__ x, const float* __restrict__ p,
    unsigned short* __restrict__ xb, unsigned short* __restrict__ pb,
    float* __restrict__ xsq, float* __restrict__ psq) {
  const int rg = blockIdx.x;
  const int t = threadIdx.x;
  const int row = t >> 4;
  const int kq  = t & 15;

  const float* src;
  unsigned short* dst;
  float* sq;
  if (rg < B_DIM / 16) {
    src = x + (size_t)rg * 16 * D_DIM;
    dst = xb + (size_t)rg * 4096;          // 16*256 elems per rg
    sq  = xsq + rg * 16;
  } else {
    const int r = rg - B_DIM / 16;
    src = p + (size_t)r * 16 * D_DIM;
    dst = pb + (size_t)r * 4096;
    sq  = psq + r * 16;
  }

  float s = 0.0f;
  #pragma unroll
  for (int pass = 0; pass < 4; ++pass) {
    float4 v = *(const float4*)(src + row * D_DIM + pass * 64 + kq * 4);
    s += v.x * v.x + v.y * v.y + v.z * v.z + v.w * v.w;
    ushort4 o;
    o.x = f2bf_rne(v.x); o.y = f2bf_rne(v.y);
    o.z = f2bf_rne(v.z); o.w = f2bf_rne(v.w);
    const int kc = pass * 8 + (kq >> 1);
    *(ushort4*)(dst + kc * 128 + row * 8 + (kq & 1) * 4) = o;
  }
  // reduce across the 16 kq-threads of this row (contiguous lanes)
  s += __shfl_xor(s, 1);
  s += __shfl_xor(s, 2);
  s += __shfl_xor(s, 4);
  s += __shfl_xor(s, 8);
  if (kq == 0) sq[row] = s;
}

// Barrier-free GEMM: each wave owns a 64x64 output tile, reads fragments
// directly from the interleaved global layout (1KB coalesced loads, no LDS),
// accumulates 4x4 16x16x32 bf16 MFMA frags, fused L2-distance epilogue.
// Overlap of MFMA / L2-fetch / HBM-write comes from TLP (3 blocks/CU) and
// natural block turnover instead of intra-block pipelining.
__global__ __launch_bounds__(256, 3) void dist_gemm(
    const unsigned short* __restrict__ A2,  // [B_DIM/16][32][16][8] bf16 bits
    const unsigned short* __restrict__ B2,  // [P_DIM/16][32][16][8] bf16 bits
    const float* __restrict__ xsq, const float* __restrict__ psq,
    float* __restrict__ out) {
  const int tid  = threadIdx.x;
  const int w    = tid >> 6;
  const int lane = tid & 63;
  const int bid  = blockIdx.x;

  // XCD-chunked map: xcd = bid&7 owns bnb {2*xcd, 2*xcd+1}; within an XCD,
  // consecutive idx pairs share am (A panel L2/L1-hot), B slice 256KB L2-hot.
  const int xcd = bid & 7;
  const int idx = bid >> 3;          // 0..511
  const int am  = idx >> 1;          // 0..255  (64-row A panel)
  const int bnb = xcd * 2 + (idx & 1);
  const int bn  = bnb * 4 + w;       // 0..63   (wave's 64-col B panel)

  // Fragment-load bases: rg block = 8KB; av[m] at kt: base + m*8192 + kt*1024.
  const char* Abase = (const char*)A2 + (size_t)am * 32768 + lane * 16;
  const char* Bbase = (const char*)B2 + (size_t)bn * 32768 + lane * 16;

  f32x4 acc[4][4];
  #pragma unroll
  for (int m = 0; m < 4; ++m)
    #pragma unroll
    for (int n = 0; n < 4; ++n) acc[m][n] = 0.0f;

  #pragma unroll
  for (int kt = 0; kt < 8; ++kt) {
    bf16x8 av[4], bv[4];
    #pragma unroll
    for (int m = 0; m < 4; ++m)
      av[m] = *(const bf16x8*)(Abase + m * 8192 + kt * 1024);
    #pragma unroll
    for (int n = 0; n < 4; ++n)
      bv[n] = *(const bf16x8*)(Bbase + n * 8192 + kt * 1024);
    #pragma unroll
    for (int m = 0; m < 4; ++m)
      #pragma unroll
      for (int n = 0; n < 4; ++n)
        acc[m][n] = __builtin_amdgcn_mfma_f32_16x16x32_bf16(av[m], bv[n], acc[m][n], 0, 0, 0);
  }

  // Epilogue: out = sqrt(max(xsq + psq - 2*xp, 0))
  // C/D layout (verified R1-R5): col = lane&15, row = (lane>>4)*4 + reg
  const int rowb = am * 64 + ((lane >> 4) << 2);  // + m*16 + j
  const int colb = bn * 64 + (lane & 15);         // + n*16
  f32x4 xs4[4];
  #pragma unroll
  for (int m = 0; m < 4; ++m)
    xs4[m] = *(const f32x4*)(xsq + rowb + m * 16);
  float psv[4];
  #pragma unroll
  for (int n = 0; n < 4; ++n) psv[n] = psq[colb + n * 16];

  #pragma unroll
  for (int m = 0; m < 4; ++m) {
    #pragma unroll
    for (int j = 0; j < 4; ++j) {
      float* orow = out + (size_t)(rowb + m * 16 + j) * P_DIM + colb;
      #pragma unroll
      for (int n = 0; n < 4; ++n) {
        float v = fmaf(-2.0f, acc[m][n][j], xs4[m][j] + psv[n]);
        orow[n * 16] = __builtin_sqrtf(fmaxf(v, 0.0f));
      }
    }
  }
}

extern "C" void kernel_launch(void* const* d_in, const int* in_sizes, int n_in,
                              void* d_out, int out_size, void* d_ws, size_t ws_size,
                              hipStream_t stream) {
  const float* x = (const float*)d_in[0];
  const float* p = (const float*)d_in[1];
  float* out = (float*)d_out;

  char* ws = (char*)d_ws;
  unsigned short* xb = (unsigned short*)ws;                                // 8 MB
  unsigned short* pb = (unsigned short*)(ws + (size_t)B_DIM * D_DIM * 2);  // 2 MB
  float* xsq = (float*)(ws + (size_t)(B_DIM + P_DIM) * D_DIM * 2);
  float* psq = xsq + B_DIM;

  prep_kernel<<<(B_DIM + P_DIM) / 16, 256, 0, stream>>>(x, p, xb, pb, xsq, psq);

  dist_gemm<<<4096, 256, 0, stream>>>(xb, pb, xsq, psq, out);
}

// Round 7
// 87.636 us; speedup vs baseline: 1.1928x; 1.1928x over previous
//
#include <hip/hip_runtime.h>
#include <hip/hip_bf16.h>

#define B_DIM 16384
#define P_DIM 4096
#define D_DIM 256
#define BM 256
#define BN 256
#define BK 32
#define NT (D_DIM / BK)   // 8 K-steps

typedef float f32x4 __attribute__((ext_vector_type(4)));
typedef __bf16 bf16x8 __attribute__((ext_vector_type(8)));

__device__ __forceinline__ unsigned short f2bf_rne(float f) {
  unsigned int u = __builtin_bit_cast(unsigned int, f);
  u += 0x7fffu + ((u >> 16) & 1u);
  return (unsigned short)(u >> 16);
}

// One wave per row: fp32 -> bf16 conversion + fp32 row sum-of-squares.
__global__ __launch_bounds__(256) void prep_kernel(
    const float* __restrict__ x, const float* __restrict__ p,
    unsigned short* __restrict__ xb, unsigned short* __restrict__ pb,
    float* __restrict__ xsq, float* __restrict__ psq) {
  int row  = blockIdx.x * 4 + (threadIdx.x >> 6);
  int lane = threadIdx.x & 63;
  const float4* src;
  unsigned short* dst;
  float* sq;
  if (row < B_DIM) {
    src = (const float4*)(x + (size_t)row * D_DIM);
    dst = xb + (size_t)row * D_DIM;
    sq  = xsq + row;
  } else {
    int r = row - B_DIM;
    src = (const float4*)(p + (size_t)r * D_DIM);
    dst = pb + (size_t)r * D_DIM;
    sq  = psq + r;
  }
  float4 v = src[lane];
  ushort4 o;
  o.x = f2bf_rne(v.x); o.y = f2bf_rne(v.y);
  o.z = f2bf_rne(v.z); o.w = f2bf_rne(v.w);
  ((ushort4*)dst)[lane] = o;
  float s = v.x * v.x + v.y * v.y + v.z * v.z + v.w * v.w;
  #pragma unroll
  for (int off = 32; off > 0; off >>= 1) s += __shfl_down(s, off);
  if (lane == 0) *sq = s;
}

__device__ __forceinline__ void async16(const unsigned short* g, const void* l) {
  __builtin_amdgcn_global_load_lds(
      (const __attribute__((address_space(1))) void*)g,
      (__attribute__((address_space(3))) void*)l,
      16, 0, 0);
}

// 256x256 tile, 8 waves (2x4), BK=32, dbuf 64KB LDS, counted-vmcnt pipeline.
// MFMA operands SWAPPED (D = P.X^T transposed) so each lane holds 4
// consecutive p-cols -> epilogue is 32 f32x4 stores/lane (no vmcnt-cap
// stall; wave retires with stores in flight, draining under next block).
__global__ __launch_bounds__(512, 2) void dist_gemm(
    const unsigned short* __restrict__ A,   // [B_DIM][D_DIM] bf16 bits
    const unsigned short* __restrict__ Bm,  // [P_DIM][D_DIM] bf16 bits
    const float* __restrict__ xsq, const float* __restrict__ psq,
    float* __restrict__ out) {
  __shared__ __align__(16) char lds[2][2][16384];  // [buf][A|B][256r x 64B]

  const int tid  = threadIdx.x;
  const int w    = tid >> 6;        // 0..7
  const int lane = tid & 63;
  const int bid  = blockIdx.x;

  // XCD-chunked bijective swizzle: 1024 blocks, 8 XCDs, 128 blocks each.
  // Within an XCD: 16 consecutive blocks share bm (A panel L2-hot); the
  // whole B' (2 MB) is L2-resident per XCD.
  const int swz = (bid & 7) * 128 + (bid >> 3);
  const int bm  = swz >> 4;   // 0..63
  const int bn  = swz & 15;   // 0..15

  const int wr = w >> 2;      // 0..1  (row half: 128 rows)
  const int wc = w & 3;       // 0..3  (col quarter: 64 cols)

  // ---- staging geometry (linear LDS dest, pre-swizzled global source) ----
  // q = l*8192 + w*1024 + lane*16 byte within 16KB tile [256 rows][64 B].
  // swizzle: col-chunk ^= (row&3)<<4  (both sides, rule 21).
  const int rstg = w * 16 + (lane >> 2);               // + l*128
  const int cstg = (((lane & 3) << 4) ^ ((rstg & 3) << 4)) >> 1;  // elem col
  const unsigned short* aP[2];
  const unsigned short* bP[2];
  #pragma unroll
  for (int l = 0; l < 2; ++l) {
    aP[l] = A  + (size_t)(bm * BM + l * 128 + rstg) * D_DIM + cstg;
    bP[l] = Bm + (size_t)(bn * BN + l * 128 + rstg) * D_DIM + cstg;
  }

#define STAGE(bufi, ktE) do { _Pragma("unroll")                                \
    for (int l = 0; l < 2; ++l) {                                              \
      async16(aP[l] + (ktE), (const void*)(&lds[bufi][0][0] + l * 8192 + w * 1024)); \
      async16(bP[l] + (ktE), (const void*)(&lds[bufi][1][0] + l * 8192 + w * 1024)); \
    } } while (0)

  // ---- fragment read geometry ----
  // A frag m: row R = wr*128 + m*16 + (lane&15); B frag n: R = wc*64 + n*16 + (lane&15).
  // byte addr = R*64 + koff, koff = ((lane>>4)<<4) ^ ((lane&3)<<4)  (R&3 == lane&3).
  const int arow = wr * 128 + (lane & 15);
  const int brow = wc * 64 + (lane & 15);
  const int koff = ((lane >> 4) << 4) ^ ((lane & 3) << 4);

  f32x4 acc[8][4];
  #pragma unroll
  for (int m = 0; m < 8; ++m)
    #pragma unroll
    for (int n = 0; n < 4; ++n) acc[m][n] = 0.0f;

  // Prologue: stage k-tile 0 into buf 0.
  STAGE(0, 0);
  asm volatile("s_waitcnt vmcnt(0)" ::: "memory");
  __builtin_amdgcn_s_barrier();
  __builtin_amdgcn_sched_barrier(0);

  #pragma unroll
  for (int t = 0; t < NT; ++t) {
    if (t < NT - 1) STAGE((t + 1) & 1, (t + 1) * BK);
    if (t > 0) {
      // stage(t) done; stage(t+1)'s 4 loads stay in flight.
      if (t < NT - 1) asm volatile("s_waitcnt vmcnt(4)" ::: "memory");
      else            asm volatile("s_waitcnt vmcnt(0)" ::: "memory");
      __builtin_amdgcn_s_barrier();
      __builtin_amdgcn_sched_barrier(0);
    }
    const char* La = &lds[t & 1][0][0];
    const char* Lb = &lds[t & 1][1][0];
    bf16x8 av[8], bv[4];
    #pragma unroll
    for (int m = 0; m < 8; ++m)
      av[m] = *(const bf16x8*)(La + (arow + m * 16) * 64 + koff);
    #pragma unroll
    for (int n = 0; n < 4; ++n)
      bv[n] = *(const bf16x8*)(Lb + (brow + n * 16) * 64 + koff);
    #pragma unroll
    for (int m = 0; m < 8; ++m)
      #pragma unroll
      for (int n = 0; n < 4; ++n)
        acc[m][n] = __builtin_amdgcn_mfma_f32_16x16x32_bf16(bv[n], av[m], acc[m][n], 0, 0, 0);
    if (t < NT - 1) {
      __builtin_amdgcn_sched_barrier(0);
      __builtin_amdgcn_s_barrier();   // all waves done reading buf t
      __builtin_amdgcn_sched_barrier(0);
    }
  }

  // ---- Epilogue: D transposed => lane holds 4 consecutive p-cols ----
  // frag (m,n): x-row = bm*256 + wr*128 + m*16 + (lane&15)
  //             p-col = bn*256 + wc*64 + n*16 + (lane>>4)*4 + j
  const int xrow0 = bm * BM + wr * 128 + (lane & 15);
  const int pcol0 = bn * BN + wc * 64 + ((lane >> 4) << 2);
  f32x4 ps[4];
  #pragma unroll
  for (int n = 0; n < 4; ++n)
    ps[n] = *(const f32x4*)(psq + pcol0 + n * 16);
  #pragma unroll
  for (int m = 0; m < 8; ++m) {
    const int xrow = xrow0 + m * 16;
    const float xs = xsq[xrow];
    float* orow = out + (size_t)xrow * P_DIM + pcol0;
    #pragma unroll
    for (int n = 0; n < 4; ++n) {
      f32x4 v;
      #pragma unroll
      for (int j = 0; j < 4; ++j) {
        float d = fmaf(-2.0f, acc[m][n][j], xs + ps[n][j]);
        v[j] = __builtin_sqrtf(fmaxf(d, 0.0f));
      }
      *(f32x4*)(orow + n * 16) = v;
    }
  }
#undef STAGE
}

extern "C" void kernel_launch(void* const* d_in, const int* in_sizes, int n_in,
                              void* d_out, int out_size, void* d_ws, size_t ws_size,
                              hipStream_t stream) {
  const float* x = (const float*)d_in[0];
  const float* p = (const float*)d_in[1];
  float* out = (float*)d_out;

  char* ws = (char*)d_ws;
  unsigned short* xb = (unsigned short*)ws;                                // 8 MB
  unsigned short* pb = (unsigned short*)(ws + (size_t)B_DIM * D_DIM * 2);  // 2 MB
  float* xsq = (float*)(ws + (size_t)(B_DIM + P_DIM) * D_DIM * 2);
  float* psq = xsq + B_DIM;

  prep_kernel<<<(B_DIM + P_DIM) / 4, 256, 0, stream>>>(x, p, xb, pb, xsq, psq);

  dist_gemm<<<(B_DIM / BM) * (P_DIM / BN), 512, 0, stream>>>(xb, pb, xsq, psq, out);
}